// Round 8
// baseline (1035.849 us; speedup 1.0000x reference)
//
#include <hip/hip_runtime.h>
#include <stdint.h>

#define K_DIM 4096
#define N_DIM 4096
#define M_DIM 16384  // 8 * 2048

#define BM 256
#define BN 256
#define CK 32           // chunk K-depth
#define NC (K_DIM / CK) // 128 chunks

typedef _Float16 f16x8 __attribute__((ext_vector_type(8)));
typedef float f32x4 __attribute__((ext_vector_type(4)));

// ---- fp32 -> f16 conversion, both tensors in one launch, grid-stride ------
__global__ __launch_bounds__(256) void convert_f16_kernel(
    const float* __restrict__ x, uint16_t* __restrict__ xo, long n8x,
    const float* __restrict__ w, uint16_t* __restrict__ wo, long n8w) {
    const long stride = (long)gridDim.x * 256;
    const long total = n8x + n8w;
    for (long i = (long)blockIdx.x * 256 + threadIdx.x; i < total; i += stride) {
        const float4* src;
        uint4* dst;
        long j;
        if (i < n8x) {
            src = (const float4*)x; dst = (uint4*)xo; j = i;
        } else {
            src = (const float4*)w; dst = (uint4*)wo; j = i - n8x;
        }
        float4 a = src[2 * j];
        float4 b = src[2 * j + 1];
        float v[8] = {a.x, a.y, a.z, a.w, b.x, b.y, b.z, b.w};
        uint16_t h[8];
#pragma unroll
        for (int q = 0; q < 8; ++q) {
            _Float16 f = (_Float16)v[q];  // RNE v_cvt_f16_f32
            h[q] = __builtin_bit_cast(uint16_t, f);
        }
        uint4 hv;
        hv.x = (uint32_t)h[0] | ((uint32_t)h[1] << 16);
        hv.y = (uint32_t)h[2] | ((uint32_t)h[3] << 16);
        hv.z = (uint32_t)h[4] | ((uint32_t)h[5] << 16);
        hv.w = (uint32_t)h[6] | ((uint32_t)h[7] << 16);
        dst[j] = hv;
    }
}

// ---- 256x256 tile, K=32 chunks, 4-deep LDS ring, counted-vmcnt GEMM -------
// LDS chunk = [256 rows][32 f16] = 64B rows, 4x 16B slots/row.
// T2 swizzle for 64B rows: slot' = slot ^ ((row>>1)&3)  (both-sides, rule 21:
// gload_lds dest linear, global source col pre-swizzled, ds_read applies same
// XOR). Gives 8 lanes/bank-group on ds_read_b128 == conflict-free density.
// Phase c (c = 0..NC-1), slot s = c&3:
//   barrier(α)                  // all waves done ds_reading chunk c-1
//   STAGE chunk c+3 -> slot s+3 // overwrites chunk c-1's slot: safe per α
//   s_waitcnt vmcnt(12)         // own 4 loads of chunk c done; 12 stay in flight
//   barrier(β)                  // chunk c visible to all waves
//   12x ds_read_b128 ; lgkmcnt(0); sched_barrier; setprio(1); 32 MFMA; setprio(0)
// Steady state: vmcnt never drains below 12 in the loop (T4).

__global__ __launch_bounds__(512, 2) void gemm_kernel(
    const uint16_t* __restrict__ A, const uint16_t* __restrict__ B,
    const float* __restrict__ scale_p, float* __restrict__ out) {
    __shared__ __align__(16) uint16_t sA[4][256 * CK];  // 4 x 16 KiB
    __shared__ __align__(16) uint16_t sB[4][256 * CK];  // 4 x 16 KiB

    const int tid = threadIdx.x;
    const int lane = tid & 63;
    const int wave = tid >> 6;  // 0..7
    const int wr = wave >> 2;   // 0..1  (M half: 128 rows)
    const int wc = wave & 3;    // 0..3  (N quarter: 64 cols)

    // T1: XCD-aware bijective swizzle (nwg = 1024, %8 == 0)
    const int bid = blockIdx.x;
    const int swz = (bid & 7) * 128 + (bid >> 3);
    const int bm = swz >> 4;  // 0..63
    const int bn = swz & 15;  // 0..15

    // staging: granule g = round*512 + tid; row = g>>2 (256 rows), slot = g&3
    const int srow = tid >> 2;  // row for round 0 (round 1 adds 128)
    const int swcol = (((tid & 3) ^ ((srow >> 1) & 3)) << 3);  // elems
    const uint16_t* gA0 = A + (size_t)(bm * BM + srow) * K_DIM + swcol;
    const uint16_t* gB0 = B + (size_t)(bn * BN + srow) * K_DIM + swcol;
    const int ldst = tid * 16;  // LDS byte offset, round 0 (round 1 adds 8192)

#define GLL(gp, lp)                                                   \
    __builtin_amdgcn_global_load_lds(                                 \
        (const __attribute__((address_space(1))) void*)(gp),          \
        (__attribute__((address_space(3))) void*)(lp), 16, 0, 0);

#define STAGE(kc)                                                     \
    {                                                                 \
        char* _sa = (char*)&sA[(kc) & 3][0];                          \
        char* _sb = (char*)&sB[(kc) & 3][0];                          \
        const size_t _ko = (size_t)(kc) * CK;                         \
        GLL(gA0 + _ko, _sa + ldst)                                    \
        GLL(gA0 + _ko + (size_t)128 * K_DIM, _sa + 8192 + ldst)       \
        GLL(gB0 + _ko, _sb + ldst)                                    \
        GLL(gB0 + _ko + (size_t)128 * K_DIM, _sb + 8192 + ldst)       \
    }

    // fragment addressing: row = base + fr with base%16==0 -> xor term per-lane
    const int fr = lane & 15;
    const int kh = lane >> 4;
    const int xo16 = (kh ^ ((fr >> 1) & 3)) << 4;       // swizzled 16B slot
    const int aRow = (wr * 128 + fr) * 64 + xo16;       // byte base in A chunk
    const int bRow = (wc * 64 + fr) * 64 + xo16;        // byte base in B chunk

    f32x4 acc[8][4] = {};
    const float s = *scale_p;

    // prologue: 3 chunks in flight
    STAGE(0)
    STAGE(1)
    STAGE(2)

    for (int c = 0; c < NC; ++c) {
        __builtin_amdgcn_s_barrier();  // α: chunk c-1 reads complete everywhere
        STAGE((c + 3) & (NC - 1))      // wraps to dummy re-stage for last 3
        asm volatile("s_waitcnt vmcnt(12)" ::: "memory");  // chunk c landed (own)
        __builtin_amdgcn_s_barrier();  // β: chunk c visible to all waves

        const char* pa = (const char*)&sA[c & 3][0] + aRow;
        const char* pb = (const char*)&sB[c & 3][0] + bRow;
        f16x8 b[4], a[8];
#pragma unroll
        for (int j = 0; j < 4; ++j) b[j] = *(const f16x8*)(pb + j * 1024);
#pragma unroll
        for (int f = 0; f < 8; ++f) a[f] = *(const f16x8*)(pa + f * 1024);

        asm volatile("s_waitcnt lgkmcnt(0)" ::: "memory");
        __builtin_amdgcn_sched_barrier(0);
        __builtin_amdgcn_s_setprio(1);
#pragma unroll
        for (int f = 0; f < 8; ++f)
#pragma unroll
            for (int j = 0; j < 4; ++j)
                acc[f][j] = __builtin_amdgcn_mfma_f32_16x16x32_f16(
                    a[f], b[j], acc[f][j], 0, 0, 0);
        __builtin_amdgcn_s_setprio(0);
    }

    asm volatile("s_waitcnt vmcnt(0)" ::: "memory");  // drain dummy prefetch

    // Epilogue: C/D layout col = lane&15, row = 4*(lane>>4) + reg
    const int r0 = bm * BM + wr * 128;
    const int c0 = bn * BN + wc * 64 + fr;
    const int rs = kh * 4;
#pragma unroll
    for (int f = 0; f < 8; ++f)
#pragma unroll
        for (int j = 0; j < 4; ++j)
#pragma unroll
            for (int r = 0; r < 4; ++r)
                out[(size_t)(r0 + f * 16 + rs + r) * N_DIM + (c0 + j * 16)] =
                    acc[f][j][r] * s;
#undef STAGE
#undef GLL
}

extern "C" void kernel_launch(void* const* d_in, const int* in_sizes, int n_in,
                              void* d_out, int out_size, void* d_ws, size_t ws_size,
                              hipStream_t stream) {
    const float* x = (const float*)d_in[0];       // [8,2048,4096] fp32
    const float* qw = (const float*)d_in[1];      // [4096,4096] ternary fp32
    const float* wscale = (const float*)d_in[2];  // scalar
    float* out = (float*)d_out;

    // workspace: xf16 (128 MiB) | wf16 (32 MiB)
    uint16_t* xf16 = (uint16_t*)d_ws;
    uint16_t* wf16 = xf16 + (size_t)M_DIM * K_DIM;

    convert_f16_kernel<<<2048, 256, 0, stream>>>(
        x, xf16, (long)M_DIM * K_DIM / 8, qw, wf16, (long)N_DIM * K_DIM / 8);

    const int grid = (M_DIM / BM) * (N_DIM / BN);  // 1024
    gemm_kernel<<<grid, 512, 0, stream>>>(xf16, wf16, wscale, out);
}

// Round 9
// 965.148 us; speedup vs baseline: 1.0733x; 1.0733x over previous
//
#include <hip/hip_runtime.h>
#include <stdint.h>

#define K_DIM 4096
#define N_DIM 4096
#define M_DIM 16384  // 8 * 2048

#define BM 256
#define BN 256
#define CK 32           // chunk K-depth
#define NC (K_DIM / CK) // 128 chunks

typedef _Float16 f16x8 __attribute__((ext_vector_type(8)));
typedef float f32x4 __attribute__((ext_vector_type(4)));

// ---- fp32 -> f16 conversion, both tensors in one launch, grid-stride ------
__global__ __launch_bounds__(256) void convert_f16_kernel(
    const float* __restrict__ x, uint16_t* __restrict__ xo, long n8x,
    const float* __restrict__ w, uint16_t* __restrict__ wo, long n8w) {
    const long stride = (long)gridDim.x * 256;
    const long total = n8x + n8w;
    for (long i = (long)blockIdx.x * 256 + threadIdx.x; i < total; i += stride) {
        const float4* src;
        uint4* dst;
        long j;
        if (i < n8x) {
            src = (const float4*)x; dst = (uint4*)xo; j = i;
        } else {
            src = (const float4*)w; dst = (uint4*)wo; j = i - n8x;
        }
        float4 a = src[2 * j];
        float4 b = src[2 * j + 1];
        float v[8] = {a.x, a.y, a.z, a.w, b.x, b.y, b.z, b.w};
        uint16_t h[8];
#pragma unroll
        for (int q = 0; q < 8; ++q) {
            _Float16 f = (_Float16)v[q];  // RNE v_cvt_f16_f32
            h[q] = __builtin_bit_cast(uint16_t, f);
        }
        uint4 hv;
        hv.x = (uint32_t)h[0] | ((uint32_t)h[1] << 16);
        hv.y = (uint32_t)h[2] | ((uint32_t)h[3] << 16);
        hv.z = (uint32_t)h[4] | ((uint32_t)h[5] << 16);
        hv.w = (uint32_t)h[6] | ((uint32_t)h[7] << 16);
        dst[j] = hv;
    }
}

// ---- 256x256 tile, K=32 chunks, 4-deep LDS ring, counted-vmcnt GEMM -------
// LDS chunk = [256 rows][32 f16] = 64B rows, 4x 16B slots/row.
// T2 swizzle for 64B rows: slot' = slot ^ ((row>>1)&3)  (rule 21 both-sides:
// gload_lds dest linear, global source col pre-swizzled, ds_read same XOR).
// 8 granules per 16B bank-set on ds_read_b128 == conflict-free (measured 0).
// Phase c (ONE barrier per phase; m201 ordering restored):
//   ds_read chunk c ×12        // issues under prev phase's MFMA pipe drain
//   STAGE chunk c+3 -> slot    // overwrite of c-1's slot safe: all waves'
//                              // reads of c-1 retired before prev barrier
//   lgkmcnt(0); sched_barrier  // rule 18
//   setprio(1); 32 MFMA; setprio(0)
//   vmcnt(8)                   // retire chunk c+1 (c+2,c+3 stay in flight: T4)
//   s_barrier                  // publish chunk c+1 to all waves
__global__ __launch_bounds__(512, 2) void gemm_kernel(
    const uint16_t* __restrict__ A, const uint16_t* __restrict__ B,
    const float* __restrict__ scale_p, float* __restrict__ out) {
    __shared__ __align__(16) uint16_t sA[4][256 * CK];  // 4 x 16 KiB
    __shared__ __align__(16) uint16_t sB[4][256 * CK];  // 4 x 16 KiB

    const int tid = threadIdx.x;
    const int lane = tid & 63;
    const int wave = tid >> 6;  // 0..7
    const int wr = wave >> 2;   // 0..1  (M half: 128 rows)
    const int wc = wave & 3;    // 0..3  (N quarter: 64 cols)

    // T1: XCD-aware bijective swizzle (nwg = 1024, %8 == 0)
    const int bid = blockIdx.x;
    const int swz = (bid & 7) * 128 + (bid >> 3);
    const int bm = swz >> 4;  // 0..63
    const int bn = swz & 15;  // 0..15

    // staging: granule g = round*512 + tid; row = g>>2 (256 rows), slot = g&3
    const int srow = tid >> 2;  // row for round 0 (round 1 adds 128)
    const int swcol = (((tid & 3) ^ ((srow >> 1) & 3)) << 3);  // elems
    const uint16_t* gA0 = A + (size_t)(bm * BM + srow) * K_DIM + swcol;
    const uint16_t* gB0 = B + (size_t)(bn * BN + srow) * K_DIM + swcol;
    const int ldst = tid * 16;  // LDS byte offset, round 0 (round 1 adds 8192)

#define GLL(gp, lp)                                                   \
    __builtin_amdgcn_global_load_lds(                                 \
        (const __attribute__((address_space(1))) void*)(gp),          \
        (__attribute__((address_space(3))) void*)(lp), 16, 0, 0);

#define STAGE(kc)                                                     \
    {                                                                 \
        char* _sa = (char*)&sA[(kc) & 3][0];                          \
        char* _sb = (char*)&sB[(kc) & 3][0];                          \
        const size_t _ko = (size_t)(kc) * CK;                         \
        GLL(gA0 + _ko, _sa + ldst)                                    \
        GLL(gA0 + _ko + (size_t)128 * K_DIM, _sa + 8192 + ldst)       \
        GLL(gB0 + _ko, _sb + ldst)                                    \
        GLL(gB0 + _ko + (size_t)128 * K_DIM, _sb + 8192 + ldst)       \
    }

    // fragment addressing: per-lane swizzled 16B slot within 64B row
    const int fr = lane & 15;
    const int kh = lane >> 4;
    const int xo16 = (kh ^ ((fr >> 1) & 3)) << 4;       // swizzled 16B slot
    const int aRow = (wr * 128 + fr) * 64 + xo16;       // byte base in A chunk
    const int bRow = (wc * 64 + fr) * 64 + xo16;        // byte base in B chunk

    f32x4 acc[8][4] = {};
    const float s = *scale_p;

    // prologue: 3 chunks in flight, publish chunk 0
    STAGE(0)
    STAGE(1)
    STAGE(2)
    asm volatile("s_waitcnt vmcnt(8)" ::: "memory");  // chunk 0 landed (own)
    __builtin_amdgcn_s_barrier();

    for (int c = 0; c < NC; ++c) {
        const char* pa = (const char*)&sA[c & 3][0] + aRow;
        const char* pb = (const char*)&sB[c & 3][0] + bRow;
        f16x8 b[4], a[8];
#pragma unroll
        for (int j = 0; j < 4; ++j) b[j] = *(const f16x8*)(pb + j * 1024);
#pragma unroll
        for (int f = 0; f < 8; ++f) a[f] = *(const f16x8*)(pa + f * 1024);

        STAGE((c + 3) & (NC - 1))  // wraps to dummy re-stage for last 3

        asm volatile("s_waitcnt lgkmcnt(0)" ::: "memory");
        __builtin_amdgcn_sched_barrier(0);
        __builtin_amdgcn_s_setprio(1);
#pragma unroll
        for (int f = 0; f < 8; ++f)
#pragma unroll
            for (int j = 0; j < 4; ++j)
                acc[f][j] = __builtin_amdgcn_mfma_f32_16x16x32_f16(
                    a[f], b[j], acc[f][j], 0, 0, 0);
        __builtin_amdgcn_s_setprio(0);

        asm volatile("s_waitcnt vmcnt(8)" ::: "memory");  // retire chunk c+1
        __builtin_amdgcn_s_barrier();                     // publish it
    }

    asm volatile("s_waitcnt vmcnt(0)" ::: "memory");  // drain dummy prefetch

    // Epilogue: C/D layout col = lane&15, row = 4*(lane>>4) + reg
    const int r0 = bm * BM + wr * 128;
    const int c0 = bn * BN + wc * 64 + fr;
    const int rs = kh * 4;
#pragma unroll
    for (int f = 0; f < 8; ++f)
#pragma unroll
        for (int j = 0; j < 4; ++j)
#pragma unroll
            for (int r = 0; r < 4; ++r)
                out[(size_t)(r0 + f * 16 + rs + r) * N_DIM + (c0 + j * 16)] =
                    acc[f][j][r] * s;
#undef STAGE
#undef GLL
}

extern "C" void kernel_launch(void* const* d_in, const int* in_sizes, int n_in,
                              void* d_out, int out_size, void* d_ws, size_t ws_size,
                              hipStream_t stream) {
    const float* x = (const float*)d_in[0];       // [8,2048,4096] fp32
    const float* qw = (const float*)d_in[1];      // [4096,4096] ternary fp32
    const float* wscale = (const float*)d_in[2];  // scalar
    float* out = (float*)d_out;

    // workspace: xf16 (128 MiB) | wf16 (32 MiB)
    uint16_t* xf16 = (uint16_t*)d_ws;
    uint16_t* wf16 = xf16 + (size_t)M_DIM * K_DIM;

    convert_f16_kernel<<<2048, 256, 0, stream>>>(
        x, xf16, (long)M_DIM * K_DIM / 8, qw, wf16, (long)N_DIM * K_DIM / 8);

    const int grid = (M_DIM / BM) * (N_DIM / BN);  // 1024
    gemm_kernel<<<grid, 512, 0, stream>>>(xf16, wf16, wscale, out);
}

// Round 12
// 919.234 us; speedup vs baseline: 1.1269x; 1.0499x over previous
//
#include <hip/hip_runtime.h>
#include <stdint.h>

#define K_DIM 4096
#define N_DIM 4096
#define M_DIM 16384  // 8 * 2048

#define BM 256
#define BN 256
#define CK 32           // chunk K-depth
#define NC (K_DIM / CK) // 128 chunks

typedef _Float16 f16x8 __attribute__((ext_vector_type(8)));
typedef float f32x4 __attribute__((ext_vector_type(4)));

// ---- fp32 -> f16 conversion, both tensors in one launch, grid-stride ------
__global__ __launch_bounds__(256) void convert_f16_kernel(
    const float* __restrict__ x, uint16_t* __restrict__ xo, long n8x,
    const float* __restrict__ w, uint16_t* __restrict__ wo, long n8w) {
    const long stride = (long)gridDim.x * 256;
    const long total = n8x + n8w;
    for (long i = (long)blockIdx.x * 256 + threadIdx.x; i < total; i += stride) {
        const float4* src;
        uint4* dst;
        long j;
        if (i < n8x) {
            src = (const float4*)x; dst = (uint4*)xo; j = i;
        } else {
            src = (const float4*)w; dst = (uint4*)wo; j = i - n8x;
        }
        float4 a = src[2 * j];
        float4 b = src[2 * j + 1];
        float v[8] = {a.x, a.y, a.z, a.w, b.x, b.y, b.z, b.w};
        uint16_t h[8];
#pragma unroll
        for (int q = 0; q < 8; ++q) {
            _Float16 f = (_Float16)v[q];  // RNE v_cvt_f16_f32
            h[q] = __builtin_bit_cast(uint16_t, f);
        }
        uint4 hv;
        hv.x = (uint32_t)h[0] | ((uint32_t)h[1] << 16);
        hv.y = (uint32_t)h[2] | ((uint32_t)h[3] << 16);
        hv.z = (uint32_t)h[4] | ((uint32_t)h[5] << 16);
        hv.w = (uint32_t)h[6] | ((uint32_t)h[7] << 16);
        dst[j] = hv;
    }
}

// ---- 256x256 tile, K=32 chunks, 4-deep LDS ring, reg-double-buffered ------
// LDS chunk = [256 rows][32 f16] = 64B rows, 4x 16B slots/row.
// T2 swizzle: slot' = slot ^ ((row>>1)&3) (rule 21 both-sides; measured 0
// bank conflicts). Phase c (one barrier; frags for chunk c preloaded):
//   ds_read chunk c+1 -> NXT regs   // hides under MFMA below
//   STAGE chunk c+3                 // vmcnt +4
//   sched_barrier(0)                // pin mem-issue before MFMA cluster
//   setprio(1); 32 MFMA on CUR; setprio(0)
//   lgkmcnt(0)                      // own reads retired (fences slot reuse)
//   vmcnt(4)                        // chunk c+2 landed (c+3 stays in flight)
//   s_barrier                       // publish chunk c+2
// Ledger: NXT-read of c+1 follows prev phase's vmcnt(4)+bar (published);
// STAGE(c+3) overwrites c-1's slot, whose reads retired before prev bar's
// lgkmcnt(0). vmcnt never drains below 4 in-loop (T4).
__global__ __launch_bounds__(512, 2) void gemm_kernel(
    const uint16_t* __restrict__ A, const uint16_t* __restrict__ B,
    const float* __restrict__ scale_p, float* __restrict__ out) {
    __shared__ __align__(16) uint16_t sA[4][256 * CK];  // 4 x 16 KiB
    __shared__ __align__(16) uint16_t sB[4][256 * CK];  // 4 x 16 KiB

    const int tid = threadIdx.x;
    const int lane = tid & 63;
    const int wave = tid >> 6;  // 0..7
    const int wr = wave >> 2;   // 0..1  (M half: 128 rows)
    const int wc = wave & 3;    // 0..3  (N quarter: 64 cols)

    // T1: XCD-aware bijective swizzle (nwg = 1024, %8 == 0)
    const int bid = blockIdx.x;
    const int swz = (bid & 7) * 128 + (bid >> 3);
    const int bm = swz >> 4;  // 0..63
    const int bn = swz & 15;  // 0..15

    // staging: granule g = round*512 + tid; row = g>>2 (256 rows), slot = g&3
    const int srow = tid >> 2;  // row for round 0 (round 1 adds 128)
    const int swcol = (((tid & 3) ^ ((srow >> 1) & 3)) << 3);  // elems
    const uint16_t* gA0 = A + (size_t)(bm * BM + srow) * K_DIM + swcol;
    const uint16_t* gB0 = B + (size_t)(bn * BN + srow) * K_DIM + swcol;
    const int ldst = tid * 16;  // LDS byte offset, round 0 (round 1 adds 8192)

#define GLL(gp, lp)                                                   \
    __builtin_amdgcn_global_load_lds(                                 \
        (const __attribute__((address_space(1))) void*)(gp),          \
        (__attribute__((address_space(3))) void*)(lp), 16, 0, 0);

#define STAGE(kc)                                                     \
    {                                                                 \
        char* _sa = (char*)&sA[(kc) & 3][0];                          \
        char* _sb = (char*)&sB[(kc) & 3][0];                          \
        const size_t _ko = (size_t)(kc) * CK;                         \
        GLL(gA0 + _ko, _sa + ldst)                                    \
        GLL(gA0 + _ko + (size_t)128 * K_DIM, _sa + 8192 + ldst)       \
        GLL(gB0 + _ko, _sb + ldst)                                    \
        GLL(gB0 + _ko + (size_t)128 * K_DIM, _sb + 8192 + ldst)       \
    }

    // fragment addressing: per-lane swizzled 16B slot within 64B row
    const int fr = lane & 15;
    const int kh = lane >> 4;
    const int xo16 = (kh ^ ((fr >> 1) & 3)) << 4;       // swizzled 16B slot
    const int aRow = (wr * 128 + fr) * 64 + xo16;       // byte base in A chunk
    const int bRow = (wc * 64 + fr) * 64 + xo16;        // byte base in B chunk

    f32x4 acc[8][4] = {};
    const float s = *scale_p;

    f16x8 a0[8], b0[4], a1[8], b1[4];  // double-buffered fragment sets

#define DSREAD(kc, AS, BS)                                            \
    {                                                                 \
        const char* _pa = (const char*)&sA[(kc) & 3][0] + aRow;       \
        const char* _pb = (const char*)&sB[(kc) & 3][0] + bRow;       \
        _Pragma("unroll") for (int j = 0; j < 4; ++j)                 \
            BS[j] = *(const f16x8*)(_pb + j * 1024);                  \
        _Pragma("unroll") for (int f = 0; f < 8; ++f)                 \
            AS[f] = *(const f16x8*)(_pa + f * 1024);                  \
    }

#define PHASE(c, ACUR, BCUR, ANXT, BNXT)                              \
    {                                                                 \
        DSREAD((c) + 1, ANXT, BNXT)                                   \
        STAGE(((c) + 3) & (NC - 1))                                   \
        __builtin_amdgcn_sched_barrier(0);                            \
        __builtin_amdgcn_s_setprio(1);                                \
        _Pragma("unroll") for (int f = 0; f < 8; ++f)                 \
            _Pragma("unroll") for (int j = 0; j < 4; ++j)             \
                acc[f][j] = __builtin_amdgcn_mfma_f32_16x16x32_f16(   \
                    ACUR[f], BCUR[j], acc[f][j], 0, 0, 0);            \
        __builtin_amdgcn_s_setprio(0);                                \
        asm volatile("s_waitcnt lgkmcnt(0)" ::: "memory");            \
        asm volatile("s_waitcnt vmcnt(4)" ::: "memory");              \
        __builtin_amdgcn_s_barrier();                                 \
    }

    // prologue: 3 chunks in flight; publish chunks 0,1; preload chunk 0
    STAGE(0)
    STAGE(1)
    STAGE(2)
    asm volatile("s_waitcnt vmcnt(4)" ::: "memory");  // chunks 0,1 landed
    __builtin_amdgcn_s_barrier();
    DSREAD(0, a0, b0)

    for (int t = 0; t < NC / 2; ++t) {
        const int c = 2 * t;
        PHASE(c, a0, b0, a1, b1)
        PHASE(c + 1, a1, b1, a0, b0)
    }

    asm volatile("s_waitcnt vmcnt(0)" ::: "memory");  // drain dummy prefetch

    // Epilogue: C/D layout col = lane&15, row = 4*(lane>>4) + reg
    const int r0 = bm * BM + wr * 128;
    const int c0 = bn * BN + wc * 64 + fr;
    const int rs = kh * 4;
#pragma unroll
    for (int f = 0; f < 8; ++f)
#pragma unroll
        for (int j = 0; j < 4; ++j)
#pragma unroll
            for (int r = 0; r < 4; ++r)
                out[(size_t)(r0 + f * 16 + rs + r) * N_DIM + (c0 + j * 16)] =
                    acc[f][j][r] * s;
#undef PHASE
#undef DSREAD
#undef STAGE
#undef GLL
}

extern "C" void kernel_launch(void* const* d_in, const int* in_sizes, int n_in,
                              void* d_out, int out_size, void* d_ws, size_t ws_size,
                              hipStream_t stream) {
    const float* x = (const float*)d_in[0];       // [8,2048,4096] fp32
    const float* qw = (const float*)d_in[1];      // [4096,4096] ternary fp32
    const float* wscale = (const float*)d_in[2];  // scalar
    float* out = (float*)d_out;

    // workspace: xf16 (128 MiB) | wf16 (32 MiB)
    uint16_t* xf16 = (uint16_t*)d_ws;
    uint16_t* wf16 = xf16 + (size_t)M_DIM * K_DIM;

    convert_f16_kernel<<<2048, 256, 0, stream>>>(
        x, xf16, (long)M_DIM * K_DIM / 8, qw, wf16, (long)N_DIM * K_DIM / 8);

    const int grid = (M_DIM / BM) * (N_DIM / BN);  // 1024
    gemm_kernel<<<grid, 512, 0, stream>>>(xf16, wf16, wscale, out);
}